// Round 13
// baseline (249.385 us; speedup 1.0000x reference)
//
#include <hip/hip_runtime.h>
#include <stdint.h>

// SelfAttentionBlock: B=4, C=256, H=W=64 (N=4096), CQK=32.
//   wcvt: W fp32->f16 (Wh), 80 blocks.
//   proj: x-transpose fused in-kernel (32KB swizzled LDS) + register MFMA GEMM
//         -> Qt[n][32]*log2e, Kt[n][32], Vp packed PV-B-fragment order.
//   attn: flash-decoding at BLOCK level: grid 512 = (jhalf, b, 64-i strip).
//         Each block = r11 structure (512 thr, 2 j-groups x 4 waves, 16 steps
//         of 64 j, V direct from L2 via Vp frags, K reg prefetch, swapped QK^T,
//         shuffle-free defer-max softmax, P dbuf LDS, group-local counter sync).
//         2 blocks/CU (LDS 68.6KB, VGPR capped 128 via launch_bounds(512,4))
//         -> 4 waves/SIMD of INDEPENDENT work. Block writes unnormalized
//         partial O (f16) + per-row (M,L) to ws.
//   combine: merges the 2 j-halves, normalizes, gamma*o + x -> out.

#define NB 4
#define CD 256
#define ND 4096
#define CQ 32
#define LOG2E 1.4426950408889634f

typedef __attribute__((ext_vector_type(4))) float f32x4;
typedef __attribute__((ext_vector_type(8))) _Float16 f16x8;
typedef __attribute__((ext_vector_type(4))) unsigned short u16x4;
typedef __attribute__((ext_vector_type(8))) unsigned short u16x8;
typedef __attribute__((ext_vector_type(2))) unsigned int u32x2;
typedef __attribute__((ext_vector_type(4))) unsigned int u32x4;
typedef __attribute__((ext_vector_type(4))) int i32x4;

static __device__ __forceinline__ unsigned short f2h(float f) {
    union { _Float16 h; unsigned short u; } cv; cv.h = (_Float16)f; return cv.u;
}
static __device__ __forceinline__ float h2f(unsigned short u) {
    union { unsigned short u; _Float16 h; } cv; cv.u = u; return (float)cv.h;
}
static __device__ __forceinline__ float fexp2(float xv) {
    float r; asm("v_exp_f32 %0, %1" : "=v"(r) : "v"(xv)); return r;
}

// ---------------- wcvt: W fp32 -> f16 ----------------
__global__ __launch_bounds__(256) void wcvt_kernel(
    const float* __restrict__ wq, const float* __restrict__ wk,
    const float* __restrict__ wv, unsigned short* __restrict__ Wh)
{
    const int idx = blockIdx.x * 256 + threadIdx.x;   // 80 blocks
    const int m = idx >> 6, kq = (idx & 63) << 2;
    const float* src = (m < 32) ? (wq + (size_t)m * CD + kq)
                     : (m < 64) ? (wk + (size_t)(m - 32) * CD + kq)
                                : (wv + (size_t)(m - 64) * CD + kq);
    const f32x4 v = *reinterpret_cast<const f32x4*>(src);
    u16x4 h;
#pragma unroll
    for (int u = 0; u < 4; ++u) h[u] = f2h(v[u]);
    *reinterpret_cast<u16x4*>(Wh + (size_t)m * CD + kq) = h;
}

// ---------------- projection: fused x-transpose + register MFMA GEMM ----------------
__global__ __launch_bounds__(320) void proj_kernel(
    const float* __restrict__ x, const unsigned short* __restrict__ Wh,
    const float* __restrict__ bq, const float* __restrict__ bk,
    const float* __restrict__ bv,
    unsigned short* __restrict__ Qt, unsigned short* __restrict__ Kt,
    unsigned short* __restrict__ Vp)
{
    __shared__ __align__(16) unsigned char xls[64 * 512];   // 32KB: [n][c] f16 swizzled

    const int tid = threadIdx.x;
    const int lane = tid & 63;
    const int w = __builtin_amdgcn_readfirstlane(tid >> 6);
    const int m16 = lane & 15, g4 = lane >> 4;
    const int b = blockIdx.x >> 6, n0 = (blockIdx.x & 63) << 6;

    {   // phase 1: load + transpose-convert into LDS
        const float* xb = x + (size_t)b * CD * ND + n0;
#pragma unroll 1
        for (int idx = tid; idx < 4096; idx += 320) {
            const int c = idx >> 4, nq = (idx & 15) << 2;
            const f32x4 v = *reinterpret_cast<const f32x4*>(xb + (size_t)c * ND + nq);
#pragma unroll
            for (int r = 0; r < 4; ++r) {
                const int row = nq + r;
                const int ad = (row * 512 + c * 2) ^ ((row & 7) << 4);
                *reinterpret_cast<unsigned short*>(&xls[ad]) = f2h(v[r]);
            }
        }
    }
    __syncthreads();

    f32x4 acc[4][4];
#pragma unroll
    for (int a = 0; a < 4; ++a)
#pragma unroll
        for (int c = 0; c < 4; ++c) acc[a][c] = (f32x4){0.f, 0.f, 0.f, 0.f};

    const unsigned short* Wrow = Wh + (size_t)(w * 64 + m16) * CD;
    const int bswz = (m16 & 7) << 4;

#pragma unroll
    for (int ks = 0; ks < 8; ++ks) {
        const int ko = ks * 32 + g4 * 8;
        f16x8 af[4], bf[4];
#pragma unroll
        for (int ms = 0; ms < 4; ++ms)
            af[ms] = *reinterpret_cast<const f16x8*>(Wrow + (size_t)ms * 16 * CD + ko);
#pragma unroll
        for (int ns = 0; ns < 4; ++ns) {
            const int ad = ((ns * 16 + m16) * 512 + ko * 2) ^ bswz;
            bf[ns] = *reinterpret_cast<const f16x8*>(&xls[ad]);
        }
        if (w == 0) {
#pragma unroll
            for (int ms = 0; ms < 4; ++ms)
#pragma unroll
                for (int ns = 0; ns < 4; ++ns)
                    acc[ms][ns] = __builtin_amdgcn_mfma_f32_16x16x32_f16(
                        af[ms], bf[ns], acc[ms][ns], 0, 0, 0);
        } else {
#pragma unroll
            for (int ms = 0; ms < 4; ++ms)
#pragma unroll
                for (int ns = 0; ns < 4; ++ns)
                    acc[ms][ns] = __builtin_amdgcn_mfma_f32_16x16x32_f16(
                        bf[ns], af[ms], acc[ms][ns], 0, 0, 0);
        }
    }

    if (w == 0) {   // Q (ms 0,1) + K (ms 2,3): D[c][n], col = m16 = n
#pragma unroll
        for (int ms = 0; ms < 4; ++ms) {
            const int seg = ms * 16;
            const int mb  = seg + g4 * 4;
            const f32x4 bias = (seg < 32) ? *reinterpret_cast<const f32x4*>(bq + mb)
                                          : *reinterpret_cast<const f32x4*>(bk + (mb - 32));
#pragma unroll
            for (int ns = 0; ns < 4; ++ns) {
                const int n = n0 + ns * 16 + m16;
                u16x4 h;
                if (seg < 32) {
#pragma unroll
                    for (int r = 0; r < 4; ++r)
                        h[r] = f2h(fmaxf(acc[ms][ns][r] + bias[r], 0.f) * LOG2E);
                    *reinterpret_cast<u16x4*>(Qt + ((size_t)(b * ND + n)) * CQ + mb) = h;
                } else {
#pragma unroll
                    for (int r = 0; r < 4; ++r)
                        h[r] = f2h(fmaxf(acc[ms][ns][r] + bias[r], 0.f));
                    *reinterpret_cast<u16x4*>(Kt + ((size_t)(b * ND + n)) * CQ + (mb - 32)) = h;
                }
            }
        }
    } else {        // V: D[n][c], rows n = g4*4+r, cols c = m16
        const int cbase = (w - 1) * 64;
#pragma unroll
        for (int ms = 0; ms < 4; ++ms) {
            const int c = cbase + ms * 16 + m16;
            const float bval = bv[c];
#pragma unroll
            for (int ns = 0; ns < 4; ++ns) {
                const int n = n0 + ns * 16 + g4 * 4;
                u16x4 h;
#pragma unroll
                for (int r = 0; r < 4; ++r)
                    h[r] = f2h(fmaxf(acc[ms][ns][r] + bval, 0.f));
                unsigned short* dst = Vp
                    + ((size_t)((b * 128 + (n >> 5)) * 16 + (c >> 4))) * 512
                    + ((((n >> 3) & 3) * 16 + (c & 15)) * 8) + (n & 7);
                *reinterpret_cast<u16x4*>(dst) = h;
            }
        }
    }
}

// ---------------- flash attention main: grid 512 = (jhalf, b, istrip) ----------------
// Block processes 64 i-rows x 2048 j (its half). 512 thr, 2 j-groups x 4 waves.
// Writes unnormalized partial O (f16, [wg][c][i]) + per-row Mb/Lb.
__global__ __launch_bounds__(512, 4) void attn_kernel(
    const unsigned short* __restrict__ Qt, const unsigned short* __restrict__ Kt,
    const unsigned short* __restrict__ Vp,
    unsigned short* __restrict__ OpH, float* __restrict__ Mb, float* __restrict__ Lb)
{
    // 0..32767      p_lds   [2 groups][2 buf][64 i][128 B]  (f16, XOR-swizzled)
    // 32768..34815  scales  [2][2][64] f32
    // 34816..34879  flags   [2][2][4]  i32
    // epilogue: Ocomb [64][260] f32 @0 (aliases); mfin@66560 lfin@67072 wfac@67584
    __shared__ __align__(16) unsigned char smem[68096];
    __shared__ int gctr[2];
    float* scales = reinterpret_cast<float*>(smem + 32768);
    int*   flags  = reinterpret_cast<int*>(smem + 34816);
    float* Ocomb  = reinterpret_cast<float*>(smem);
    float* mfin   = reinterpret_cast<float*>(smem + 66560);  // [2][64]
    float* lfin   = reinterpret_cast<float*>(smem + 67072);  // [2][64]
    float* wfac   = reinterpret_cast<float*>(smem + 67584);  // [2][64]

    const int tid  = threadIdx.x;
    const int lane = tid & 63;
    const int w8   = __builtin_amdgcn_readfirstlane(tid >> 6);
    const int g    = w8 >> 2;       // j-group within the half
    const int ws   = w8 & 3;        // i-strip (QK) / c-slice (PV)
    const int m16  = lane & 15;
    const int g4   = lane >> 4;
    // XCD swizzle: 512 blocks, 64-chunks per XCD = one (jh,b) pair per XCD
    const int wg   = (blockIdx.x & 7) * 64 + (blockIdx.x >> 3);
    const int jh   = wg >> 8;
    const int b    = (wg >> 6) & 3;
    const int i0   = (wg & 63) << 6;

    if (tid < 2) gctr[tid] = 0;
    __syncthreads();   // counter init visible before any bump

    const f16x8 qfrag = *reinterpret_cast<const f16x8*>(
        Qt + ((size_t)(b * ND + i0 + ws * 16 + m16)) * CQ + g4 * 8);
    const unsigned short* kb = Kt + ((size_t)(b * ND + m16)) * CQ + g4 * 8;
    const unsigned short* vpc =
        Vp + ((size_t)(b * 128 * 16 + ws * 4)) * 512 + lane * 8;

    f32x4 oacc[4][4];
#pragma unroll
    for (int a = 0; a < 4; ++a)
#pragma unroll
        for (int c = 0; c < 4; ++c) oacc[a][c] = (f32x4){0.f, 0.f, 0.f, 0.f};
    float mrow = -1e30f;
    float lrow = 0.f;    // per-lane PARTIAL row sum; reduced in epilogue
    const f32x4 zero4 = {0.f, 0.f, 0.f, 0.f};

    const int jbase = jh * 2048 + g * 1024;   // this block-half, this group
    const int irow  = ws * 16 + m16;
    const int iswz  = (m16 & 7) << 4;

    auto LOADK = [&](f16x8 (&kr)[4], int j) {
#pragma unroll
        for (int t = 0; t < 4; ++t)
            kr[t] = *reinterpret_cast<const f16x8*>(kb + (size_t)(j + t * 16) * CQ);
    };

    // group-local sync with fast path: check once before sleeping.
    auto GSYNC = [&](int k) {
        asm volatile("s_waitcnt lgkmcnt(0)" ::: "memory");
        if (lane == 0) atomicAdd(&gctr[g], 1);
        const int tgt = (k + 1) * 4;
        int cv = __builtin_amdgcn_readfirstlane(*(volatile int*)&gctr[g]);
        while (cv < tgt) {
            __builtin_amdgcn_s_sleep(1);
            cv = __builtin_amdgcn_readfirstlane(*(volatile int*)&gctr[g]);
        }
    };

    auto STEP = [&](int k, f16x8 (&kc)[4], f16x8 (&kn)[4]) {
        const int j0  = jbase + k * 64;
        const int par = k & 1;
        unsigned char* pb = smem + g * 16384 + par * 8192;

        // issue V frag loads now; consumed after the sync (latency hidden)
        const int jblk0 = j0 >> 5;
        f16x8 vf[2][4];
#pragma unroll
        for (int jhh = 0; jhh < 2; ++jhh)
#pragma unroll
            for (int cs = 0; cs < 4; ++cs)
                vf[jhh][cs] = *reinterpret_cast<const f16x8*>(
                    vpc + (size_t)((jblk0 + jhh) * 16 + cs) * 512);
        // prefetch next step's K
        const int jn = (k < 15) ? (j0 + 64) : jbase;
        LOADK(kn, jn);

        // ---- QK^T swapped: D[j][i], col=i=irow, lane holds 16 j values ----
        f32x4 sv[4];
#pragma unroll
        for (int t = 0; t < 4; ++t)
            sv[t] = __builtin_amdgcn_mfma_f32_16x16x32_f16(kc[t], qfrag, zero4, 0, 0, 0);

        // ---- softmax (log2 domain): shuffle-free common path ----
        float pm = sv[0][0];
#pragma unroll
        for (int t = 0; t < 4; ++t)
#pragma unroll
            for (int r = 0; r < 4; ++r) pm = fmaxf(pm, sv[t][r]);
        float sc = 1.0f;
        int myresc = 0;
        if (__ballot(pm <= mrow + 8.0f) != ~0ull) {
            float pr = fmaxf(pm, __shfl_xor(pm, 16));
            pr = fmaxf(pr, __shfl_xor(pr, 32));
            const float mnew = fmaxf(mrow, pr);
            sc = fexp2(mrow - mnew);
            mrow = mnew;
            myresc = 1;
        }
        float rs = 0.f;
#pragma unroll
        for (int t = 0; t < 4; ++t)
#pragma unroll
            for (int r = 0; r < 4; ++r) { sv[t][r] = fexp2(sv[t][r] - mrow); rs += sv[t][r]; }
        lrow = lrow * sc + rs;

        // ---- P -> LDS (4x ds_write_b64, swizzled) + scale + flag ----
#pragma unroll
        for (int t = 0; t < 4; ++t) {
            u32x2 pw;
            pw[0] = __builtin_bit_cast(unsigned int,
                        __builtin_amdgcn_cvt_pkrtz(sv[t][0], sv[t][1]));
            pw[1] = __builtin_bit_cast(unsigned int,
                        __builtin_amdgcn_cvt_pkrtz(sv[t][2], sv[t][3]));
            const int lo = (irow * 128 + t * 32 + g4 * 8) ^ iswz;
            *reinterpret_cast<u32x2*>(pb + lo) = pw;
        }
        if (g4 == 0)   scales[(g * 2 + par) * 64 + irow] = sc;
        if (lane == 0) flags[(g * 2 + par) * 4 + ws] = myresc;

        GSYNC(k);   // group-local; other group + co-resident block unconstrained

        // ---- rescale oacc if any row of the group rescaled ----
        const i32x4 fl = *reinterpret_cast<const i32x4*>(flags + (g * 2 + par) * 4);
        const int anyresc = __builtin_amdgcn_readfirstlane(fl[0] | fl[1] | fl[2] | fl[3]);
        if (anyresc) {
#pragma unroll
            for (int is = 0; is < 4; ++is) {
                const f32x4 sr = *reinterpret_cast<const f32x4*>(
                    scales + (g * 2 + par) * 64 + is * 16 + g4 * 4);
#pragma unroll
                for (int r = 0; r < 4; ++r)
#pragma unroll
                    for (int cs = 0; cs < 4; ++cs) oacc[is][cs][r] *= sr[r];
            }
        }

        // ---- PV: P A-frags from LDS, V B-frags in registers ----
        __builtin_amdgcn_s_setprio(1);
#pragma unroll
        for (int jhh = 0; jhh < 2; ++jhh) {
#pragma unroll
            for (int is = 0; is < 4; ++is) {
                const int lo = ((is * 16 + m16) * 128 + jhh * 64 + g4 * 16) ^ iswz;
                const f16x8 pf = *reinterpret_cast<const f16x8*>(pb + lo);
#pragma unroll
                for (int cs = 0; cs < 4; ++cs)
                    oacc[is][cs] = __builtin_amdgcn_mfma_f32_16x16x32_f16(
                        pf, vf[jhh][cs], oacc[is][cs], 0, 0, 0);
            }
        }
        __builtin_amdgcn_s_setprio(0);
    };

    f16x8 kA[4], kB[4];
    LOADK(kA, jbase);

#pragma unroll 1
    for (int k2 = 0; k2 < 8; ++k2) {
        STEP(2 * k2,     kA, kB);
        STEP(2 * k2 + 1, kB, kA);
    }

    // ---- epilogue: reduce partial l, 2-way group merge (unnormalized) ----
    lrow += __shfl_xor(lrow, 16);
    lrow += __shfl_xor(lrow, 32);
    if (g4 == 0) { mfin[g * 64 + irow] = mrow; lfin[g * 64 + irow] = lrow; }
    __syncthreads();

    if (tid < 128) {
        const int gg = tid >> 6, i = tid & 63;
        const float m0 = mfin[i], m1 = mfin[64 + i];
        const float M  = fmaxf(m0, m1);
        const float e  = fexp2(((gg == 0) ? m0 : m1) - M);
        wfac[gg * 64 + i] = e;                     // unnormalized weight
        if (gg == 0) {
            const float e1 = fexp2(m1 - M);
            Mb[(size_t)wg * 64 + i] = M;
            Lb[(size_t)wg * 64 + i] = lfin[i] * fexp2(m0 - M) + lfin[64 + i] * e1;
        }
    }
    __syncthreads();   // loop LDS dead; Ocomb aliases it from here

    if (g == 0) {
#pragma unroll
        for (int is = 0; is < 4; ++is) {
            const f32x4 f = *reinterpret_cast<const f32x4*>(wfac + is * 16 + g4 * 4);
#pragma unroll
            for (int cs = 0; cs < 4; ++cs)
#pragma unroll
                for (int r = 0; r < 4; ++r)
                    Ocomb[(is * 16 + g4 * 4 + r) * 260 + ws * 64 + cs * 16 + m16] =
                        oacc[is][cs][r] * f[r];
        }
    }
    __syncthreads();
    if (g == 1) {
#pragma unroll
        for (int is = 0; is < 4; ++is) {
            const f32x4 f = *reinterpret_cast<const f32x4*>(wfac + 64 + is * 16 + g4 * 4);
#pragma unroll
            for (int cs = 0; cs < 4; ++cs)
#pragma unroll
                for (int r = 0; r < 4; ++r)
                    Ocomb[(is * 16 + g4 * 4 + r) * 260 + ws * 64 + cs * 16 + m16] +=
                        oacc[is][cs][r] * f[r];
        }
    }
    __syncthreads();

    // ---- write partial O as f16: OpH[wg][c][i], 16B/lane coalesced ----
#pragma unroll
    for (int pass = 0; pass < 4; ++pass) {
        const int q = tid + pass * 512;
        const int c = q >> 3, i8 = (q & 7) * 8;
        u32x4 o;
#pragma unroll
        for (int u = 0; u < 4; ++u)
            o[u] = __builtin_bit_cast(unsigned int,
                       __builtin_amdgcn_cvt_pkrtz(Ocomb[(i8 + 2 * u) * 260 + c],
                                                  Ocomb[(i8 + 2 * u + 1) * 260 + c]));
        *reinterpret_cast<u32x4*>(OpH + ((size_t)wg * 256 + c) * 64 + i8) = o;
    }
}

// ---------------- combine: merge 2 j-halves, normalize, residual ----------------
// grid 256 = (b, istrip), 256 threads.
__global__ __launch_bounds__(256) void combine_kernel(
    const unsigned short* __restrict__ OpH, const float* __restrict__ Mb,
    const float* __restrict__ Lb, const float* __restrict__ x,
    const float* __restrict__ gamma, float* __restrict__ out)
{
    __shared__ float w0[64], w1[64];
    const int tid = threadIdx.x;
    const int pb  = blockIdx.x;              // b*64 + istrip
    const int b   = pb >> 6, istrip = pb & 63;
    const int wg0 = pb, wg1 = 256 + pb;

    if (tid < 64) {
        const float m0 = Mb[(size_t)wg0 * 64 + tid], m1 = Mb[(size_t)wg1 * 64 + tid];
        const float l0 = Lb[(size_t)wg0 * 64 + tid], l1 = Lb[(size_t)wg1 * 64 + tid];
        const float M  = fmaxf(m0, m1);
        const float e0 = fexp2(m0 - M), e1 = fexp2(m1 - M);
        const float den = l0 * e0 + l1 * e1;
        w0[tid] = e0 / den;
        w1[tid] = e1 / den;
    }
    __syncthreads();

    const float gm = gamma[0];
#pragma unroll 1
    for (int pass = 0; pass < 8; ++pass) {
        const int q = tid + pass * 256;      // 2048 total; 8 elems each
        const int c = q >> 3, i8 = (q & 7) * 8;
        const u16x8 o0 = *reinterpret_cast<const u16x8*>(
            OpH + ((size_t)wg0 * 256 + c) * 64 + i8);
        const u16x8 o1 = *reinterpret_cast<const u16x8*>(
            OpH + ((size_t)wg1 * 256 + c) * 64 + i8);
        const size_t idx = ((size_t)(b * CD + c)) * ND + istrip * 64 + i8;
        const f32x4 xa = *reinterpret_cast<const f32x4*>(x + idx);
        const f32x4 xb2 = *reinterpret_cast<const f32x4*>(x + idx + 4);
        f32x4 ra, rb;
#pragma unroll
        for (int u = 0; u < 4; ++u) {
            const float v0 = h2f(o0[u]) * w0[i8 + u] + h2f(o1[u]) * w1[i8 + u];
            const float v1 = h2f(o0[u + 4]) * w0[i8 + u + 4] + h2f(o1[u + 4]) * w1[i8 + u + 4];
            ra[u] = gm * v0 + xa[u];
            rb[u] = gm * v1 + xb2[u];
        }
        *reinterpret_cast<f32x4*>(out + idx)     = ra;
        *reinterpret_cast<f32x4*>(out + idx + 4) = rb;
    }
}

extern "C" void kernel_launch(void* const* d_in, const int* in_sizes, int n_in,
                              void* d_out, int out_size, void* d_ws, size_t ws_size,
                              hipStream_t stream) {
    const float* x     = (const float*)d_in[0];
    const float* wq    = (const float*)d_in[1];
    const float* bq    = (const float*)d_in[2];
    const float* wk    = (const float*)d_in[3];
    const float* bk    = (const float*)d_in[4];
    const float* wv    = (const float*)d_in[5];
    const float* bv    = (const float*)d_in[6];
    const float* gamma = (const float*)d_in[7];

    unsigned short* Qt  = (unsigned short*)d_ws;              // 1MB (scaled by log2e)
    unsigned short* Kt  = Qt + (size_t)NB * ND * CQ;          // 1MB
    unsigned short* Vp  = Kt + (size_t)NB * ND * CQ;          // 8MB packed frags
    unsigned short* Wh  = Vp + (size_t)NB * CD * ND;          // 160KB
    unsigned short* OpH = Wh + (size_t)320 * CD;              // 512*256*64 f16 = 16.7MB
    float* Mb = (float*)(OpH + (size_t)512 * 256 * 64);       // 128KB
    float* Lb = Mb + (size_t)512 * 64;                        // 128KB
    float* out = (float*)d_out;

    wcvt_kernel<<<dim3(80),      dim3(256), 0, stream>>>(wq, wk, wv, Wh);
    proj_kernel<<<dim3(NB * 64), dim3(320), 0, stream>>>(x, Wh, bq, bk, bv, Qt, Kt, Vp);
    attn_kernel<<<dim3(512),     dim3(512), 0, stream>>>(Qt, Kt, Vp, OpH, Mb, Lb);
    combine_kernel<<<dim3(256),  dim3(256), 0, stream>>>(OpH, Mb, Lb, x, gamma, out);
}

// Round 14
// 143.998 us; speedup vs baseline: 1.7319x; 1.7319x over previous
//
#include <hip/hip_runtime.h>
#include <stdint.h>

// SelfAttentionBlock: B=4, C=256, H=W=64 (N=4096), CQK=32.
//   wcvt: W fp32->f16 (Wh), 80 blocks.
//   proj: x-transpose fused in-kernel (32KB swizzled LDS) + register MFMA GEMM
//         -> Qt[n][32]*log2e, Kt[n][32], Vp packed PV-B-fragment order.
//   attn: flash attention, 768 thr = 3 j-groups x 4 waves = 3 waves/SIMD.
//         r12 structure + V REGISTER DOUBLE-BUFFER (V(k+1) issued at top of
//         step k, consumed in PV(k+1) -> ~2400cyc load slack) + GSYNC fast
//         path. V direct from L2 (Vp frags), K reg prefetch, swapped QK^T,
//         shuffle-free defer-max softmax (log2), per-lane partial l, P dbuf
//         LDS, group-local counter sync. 3-way flash combine in epilogue.

#define NB 4
#define CD 256
#define ND 4096
#define CQ 32
#define LOG2E 1.4426950408889634f

typedef __attribute__((ext_vector_type(4))) float f32x4;
typedef __attribute__((ext_vector_type(8))) _Float16 f16x8;
typedef __attribute__((ext_vector_type(4))) unsigned short u16x4;
typedef __attribute__((ext_vector_type(2))) unsigned int u32x2;
typedef __attribute__((ext_vector_type(4))) int i32x4;

static __device__ __forceinline__ unsigned short f2h(float f) {
    union { _Float16 h; unsigned short u; } cv; cv.h = (_Float16)f; return cv.u;
}
static __device__ __forceinline__ float fexp2(float xv) {
    float r; asm("v_exp_f32 %0, %1" : "=v"(r) : "v"(xv)); return r;
}

// ---------------- wcvt: W fp32 -> f16 ----------------
__global__ __launch_bounds__(256) void wcvt_kernel(
    const float* __restrict__ wq, const float* __restrict__ wk,
    const float* __restrict__ wv, unsigned short* __restrict__ Wh)
{
    const int idx = blockIdx.x * 256 + threadIdx.x;   // 80 blocks
    const int m = idx >> 6, kq = (idx & 63) << 2;
    const float* src = (m < 32) ? (wq + (size_t)m * CD + kq)
                     : (m < 64) ? (wk + (size_t)(m - 32) * CD + kq)
                                : (wv + (size_t)(m - 64) * CD + kq);
    const f32x4 v = *reinterpret_cast<const f32x4*>(src);
    u16x4 h;
#pragma unroll
    for (int u = 0; u < 4; ++u) h[u] = f2h(v[u]);
    *reinterpret_cast<u16x4*>(Wh + (size_t)m * CD + kq) = h;
}

// ---------------- projection: fused x-transpose + register MFMA GEMM ----------------
__global__ __launch_bounds__(320) void proj_kernel(
    const float* __restrict__ x, const unsigned short* __restrict__ Wh,
    const float* __restrict__ bq, const float* __restrict__ bk,
    const float* __restrict__ bv,
    unsigned short* __restrict__ Qt, unsigned short* __restrict__ Kt,
    unsigned short* __restrict__ Vp)
{
    __shared__ __align__(16) unsigned char xls[64 * 512];   // 32KB: [n][c] f16 swizzled

    const int tid = threadIdx.x;
    const int lane = tid & 63;
    const int w = __builtin_amdgcn_readfirstlane(tid >> 6);
    const int m16 = lane & 15, g4 = lane >> 4;
    const int b = blockIdx.x >> 6, n0 = (blockIdx.x & 63) << 6;

    {   // phase 1: load + transpose-convert into LDS
        const float* xb = x + (size_t)b * CD * ND + n0;
#pragma unroll 1
        for (int idx = tid; idx < 4096; idx += 320) {
            const int c = idx >> 4, nq = (idx & 15) << 2;
            const f32x4 v = *reinterpret_cast<const f32x4*>(xb + (size_t)c * ND + nq);
#pragma unroll
            for (int r = 0; r < 4; ++r) {
                const int row = nq + r;
                const int ad = (row * 512 + c * 2) ^ ((row & 7) << 4);
                *reinterpret_cast<unsigned short*>(&xls[ad]) = f2h(v[r]);
            }
        }
    }
    __syncthreads();

    f32x4 acc[4][4];
#pragma unroll
    for (int a = 0; a < 4; ++a)
#pragma unroll
        for (int c = 0; c < 4; ++c) acc[a][c] = (f32x4){0.f, 0.f, 0.f, 0.f};

    const unsigned short* Wrow = Wh + (size_t)(w * 64 + m16) * CD;
    const int bswz = (m16 & 7) << 4;

#pragma unroll
    for (int ks = 0; ks < 8; ++ks) {
        const int ko = ks * 32 + g4 * 8;
        f16x8 af[4], bf[4];
#pragma unroll
        for (int ms = 0; ms < 4; ++ms)
            af[ms] = *reinterpret_cast<const f16x8*>(Wrow + (size_t)ms * 16 * CD + ko);
#pragma unroll
        for (int ns = 0; ns < 4; ++ns) {
            const int ad = ((ns * 16 + m16) * 512 + ko * 2) ^ bswz;
            bf[ns] = *reinterpret_cast<const f16x8*>(&xls[ad]);
        }
        if (w == 0) {
#pragma unroll
            for (int ms = 0; ms < 4; ++ms)
#pragma unroll
                for (int ns = 0; ns < 4; ++ns)
                    acc[ms][ns] = __builtin_amdgcn_mfma_f32_16x16x32_f16(
                        af[ms], bf[ns], acc[ms][ns], 0, 0, 0);
        } else {
#pragma unroll
            for (int ms = 0; ms < 4; ++ms)
#pragma unroll
                for (int ns = 0; ns < 4; ++ns)
                    acc[ms][ns] = __builtin_amdgcn_mfma_f32_16x16x32_f16(
                        bf[ns], af[ms], acc[ms][ns], 0, 0, 0);
        }
    }

    if (w == 0) {   // Q (ms 0,1) + K (ms 2,3): D[c][n], col = m16 = n
#pragma unroll
        for (int ms = 0; ms < 4; ++ms) {
            const int seg = ms * 16;
            const int mb  = seg + g4 * 4;
            const f32x4 bias = (seg < 32) ? *reinterpret_cast<const f32x4*>(bq + mb)
                                          : *reinterpret_cast<const f32x4*>(bk + (mb - 32));
#pragma unroll
            for (int ns = 0; ns < 4; ++ns) {
                const int n = n0 + ns * 16 + m16;
                u16x4 h;
                if (seg < 32) {
#pragma unroll
                    for (int r = 0; r < 4; ++r)
                        h[r] = f2h(fmaxf(acc[ms][ns][r] + bias[r], 0.f) * LOG2E);
                    *reinterpret_cast<u16x4*>(Qt + ((size_t)(b * ND + n)) * CQ + mb) = h;
                } else {
#pragma unroll
                    for (int r = 0; r < 4; ++r)
                        h[r] = f2h(fmaxf(acc[ms][ns][r] + bias[r], 0.f));
                    *reinterpret_cast<u16x4*>(Kt + ((size_t)(b * ND + n)) * CQ + (mb - 32)) = h;
                }
            }
        }
    } else {        // V: D[n][c], rows n = g4*4+r, cols c = m16
        const int cbase = (w - 1) * 64;
#pragma unroll
        for (int ms = 0; ms < 4; ++ms) {
            const int c = cbase + ms * 16 + m16;
            const float bval = bv[c];
#pragma unroll
            for (int ns = 0; ns < 4; ++ns) {
                const int n = n0 + ns * 16 + g4 * 4;
                u16x4 h;
#pragma unroll
                for (int r = 0; r < 4; ++r)
                    h[r] = f2h(fmaxf(acc[ms][ns][r] + bval, 0.f));
                unsigned short* dst = Vp
                    + ((size_t)((b * 128 + (n >> 5)) * 16 + (c >> 4))) * 512
                    + ((((n >> 3) & 3) * 16 + (c & 15)) * 8) + (n & 7);
                *reinterpret_cast<u16x4*>(dst) = h;
            }
        }
    }
}

// ---------------- flash attention: 3 j-groups x 4 waves, V reg double-buffer ----
// grid: NB*64 blocks (b, 64-row i-strip), 768 threads (12 waves, 3 waves/SIMD).
// Group g owns 64-j chunks [cbase[g], cbase[g+1]) of 64 chunks total (22/21/21).
__global__ __launch_bounds__(768) void attn_kernel(
    const unsigned short* __restrict__ Qt, const unsigned short* __restrict__ Kt,
    const unsigned short* __restrict__ Vp, const float* __restrict__ x,
    const float* __restrict__ gamma, float* __restrict__ out)
{
    // 0..49151      p_lds   [3 groups][2 buf][64 i][128 B]  (f16, XOR-swizzled)
    // 49152..50687  scales  [3][2][64] f32
    // 50688..50783  flags   [3][2][4]  i32
    // epilogue: Ocomb [64][260] f32 @0 (aliases); mfin@66560 lfin@67328 wfac@68096
    __shared__ __align__(16) unsigned char smem[68864];
    __shared__ int gctr[3];
    float* scales = reinterpret_cast<float*>(smem + 49152);
    int*   flags  = reinterpret_cast<int*>(smem + 50688);
    float* Ocomb  = reinterpret_cast<float*>(smem);
    float* mfin   = reinterpret_cast<float*>(smem + 66560);  // [3][64]
    float* lfin   = reinterpret_cast<float*>(smem + 67328);  // [3][64]
    float* wfac   = reinterpret_cast<float*>(smem + 68096);  // [3][64]

    const int tid  = threadIdx.x;
    const int lane = tid & 63;
    const int w12  = __builtin_amdgcn_readfirstlane(tid >> 6);
    const int g    = (w12 >= 8) ? 2 : (w12 >> 2);   // groups: waves 0-3,4-7,8-11
    const int ws   = (w12 >= 8) ? (w12 - 8) : (w12 & 3);
    const int m16  = lane & 15;
    const int g4   = lane >> 4;
    const int wg   = (blockIdx.x & 7) * 32 + (blockIdx.x >> 3);  // XCD swizzle
    const int b    = wg >> 6;
    const int i0   = (wg & 63) << 6;

    if (tid < 3) gctr[tid] = 0;
    __syncthreads();   // counter init visible before any bump

    // Q as B-operand: col=i=ws*16+m16, k=g4*8+u
    const f16x8 qfrag = *reinterpret_cast<const f16x8*>(
        Qt + ((size_t)(b * ND + i0 + ws * 16 + m16)) * CQ + g4 * 8);
    // K as A-operand from global: row j=m16 (+16*jt), k=g4*8+u
    const unsigned short* kb = Kt + ((size_t)(b * ND + m16)) * CQ + g4 * 8;
    // V B-frags, packed layout: 16B/lane, 1KB/wave contiguous per frag
    const unsigned short* vpc =
        Vp + ((size_t)(b * 128 * 16 + ws * 4)) * 512 + lane * 8;

    f32x4 oacc[4][4];
#pragma unroll
    for (int a = 0; a < 4; ++a)
#pragma unroll
        for (int c = 0; c < 4; ++c) oacc[a][c] = (f32x4){0.f, 0.f, 0.f, 0.f};
    float mrow = -1e30f;
    float lrow = 0.f;    // per-lane PARTIAL row sum; reduced in epilogue
    const f32x4 zero4 = {0.f, 0.f, 0.f, 0.f};

    const int cbase  = (g == 0) ? 0 : (g == 1) ? 22 : 43;
    const int nsteps = (g == 0) ? 22 : 21;
    const int irow   = ws * 16 + m16;
    const int iswz   = (m16 & 7) << 4;

    auto LOADK = [&](f16x8 (&kr)[4], int j) {
#pragma unroll
        for (int t = 0; t < 4; ++t)
            kr[t] = *reinterpret_cast<const f16x8*>(kb + (size_t)(j + t * 16) * CQ);
    };
    auto LOADV = [&](f16x8 (&vr)[2][4], int j) {
        const int jblk0 = j >> 5;
#pragma unroll
        for (int jhh = 0; jhh < 2; ++jhh)
#pragma unroll
            for (int cs = 0; cs < 4; ++cs)
                vr[jhh][cs] = *reinterpret_cast<const f16x8*>(
                    vpc + (size_t)((jblk0 + jhh) * 16 + cs) * 512);
    };

    // group-local sync with fast path: check once before sleeping.
    auto GSYNC = [&](int s) {
        asm volatile("s_waitcnt lgkmcnt(0)" ::: "memory");
        if (lane == 0) atomicAdd(&gctr[g], 1);
        const int tgt = (s + 1) * 4;
        int cv = __builtin_amdgcn_readfirstlane(*(volatile int*)&gctr[g]);
        while (cv < tgt) {
            __builtin_amdgcn_s_sleep(1);
            cv = __builtin_amdgcn_readfirstlane(*(volatile int*)&gctr[g]);
        }
    };

    // STEP(s): consume kc (K of step s) and vc (V of step s, loaded LAST step);
    // issue kn + vn for step s+1 at the top -> full-step load slack for V.
    auto STEP = [&](int s, f16x8 (&kc)[4], f16x8 (&kn)[4],
                    f16x8 (&vc)[2][4], f16x8 (&vn)[2][4]) {
        const int j0  = (cbase + s) * 64;
        const int par = s & 1;
        unsigned char* pb = smem + g * 16384 + par * 8192;

        // prefetch next step's K and V (consumed next call)
        const int jn = (s + 1 < nsteps) ? (j0 + 64) : cbase * 64;
        LOADV(vn, jn);
        LOADK(kn, jn);

        // ---- QK^T swapped: D[j][i], col=i=irow, lane holds 16 j values ----
        f32x4 sv[4];
#pragma unroll
        for (int t = 0; t < 4; ++t)
            sv[t] = __builtin_amdgcn_mfma_f32_16x16x32_f16(kc[t], qfrag, zero4, 0, 0, 0);

        // ---- softmax (log2 domain): shuffle-free common path ----
        float pm = sv[0][0];
#pragma unroll
        for (int t = 0; t < 4; ++t)
#pragma unroll
            for (int r = 0; r < 4; ++r) pm = fmaxf(pm, sv[t][r]);
        float sc = 1.0f;
        int myresc = 0;
        if (__ballot(pm <= mrow + 8.0f) != ~0ull) {
            float pr = fmaxf(pm, __shfl_xor(pm, 16));
            pr = fmaxf(pr, __shfl_xor(pr, 32));
            const float mnew = fmaxf(mrow, pr);
            sc = fexp2(mrow - mnew);
            mrow = mnew;
            myresc = 1;
        }
        float rs = 0.f;
#pragma unroll
        for (int t = 0; t < 4; ++t)
#pragma unroll
            for (int r = 0; r < 4; ++r) { sv[t][r] = fexp2(sv[t][r] - mrow); rs += sv[t][r]; }
        lrow = lrow * sc + rs;

        // ---- P -> LDS (4x ds_write_b64, swizzled) + scale + flag ----
#pragma unroll
        for (int t = 0; t < 4; ++t) {
            u32x2 pw;
            pw[0] = __builtin_bit_cast(unsigned int,
                        __builtin_amdgcn_cvt_pkrtz(sv[t][0], sv[t][1]));
            pw[1] = __builtin_bit_cast(unsigned int,
                        __builtin_amdgcn_cvt_pkrtz(sv[t][2], sv[t][3]));
            const int lo = (irow * 128 + t * 32 + g4 * 8) ^ iswz;
            *reinterpret_cast<u32x2*>(pb + lo) = pw;
        }
        if (g4 == 0)   scales[(g * 2 + par) * 64 + irow] = sc;
        if (lane == 0) flags[(g * 2 + par) * 4 + ws] = myresc;

        GSYNC(s);   // group-local; other groups unconstrained

        // ---- rescale oacc if any row of the group rescaled ----
        const i32x4 fl = *reinterpret_cast<const i32x4*>(flags + (g * 2 + par) * 4);
        const int anyresc = __builtin_amdgcn_readfirstlane(fl[0] | fl[1] | fl[2] | fl[3]);
        if (anyresc) {
#pragma unroll
            for (int is = 0; is < 4; ++is) {
                const f32x4 sr = *reinterpret_cast<const f32x4*>(
                    scales + (g * 2 + par) * 64 + is * 16 + g4 * 4);
#pragma unroll
                for (int r = 0; r < 4; ++r)
#pragma unroll
                    for (int cs = 0; cs < 4; ++cs) oacc[is][cs][r] *= sr[r];
            }
        }

        // ---- PV: P A-frags from LDS, V B-frags from regs (loaded last step) ----
        __builtin_amdgcn_s_setprio(1);
#pragma unroll
        for (int jhh = 0; jhh < 2; ++jhh) {
#pragma unroll
            for (int is = 0; is < 4; ++is) {
                const int lo = ((is * 16 + m16) * 128 + jhh * 64 + g4 * 16) ^ iswz;
                const f16x8 pf = *reinterpret_cast<const f16x8*>(pb + lo);
#pragma unroll
                for (int cs = 0; cs < 4; ++cs)
                    oacc[is][cs] = __builtin_amdgcn_mfma_f32_16x16x32_f16(
                        pf, vc[jhh][cs], oacc[is][cs], 0, 0, 0);
            }
        }
        __builtin_amdgcn_s_setprio(0);
    };

    f16x8 kA[4], kB[4], vA[2][4], vB[2][4];
    LOADK(kA, cbase * 64);
    LOADV(vA, cbase * 64);

#pragma unroll 1
    for (int s2 = 0; s2 < 11; ++s2) {
        const int s0 = 2 * s2, s1 = s0 + 1;
        if (s0 >= nsteps) break;
        STEP(s0, kA, kB, vA, vB);
        if (s1 >= nsteps) break;
        STEP(s1, kB, kA, vB, vA);
    }

    // ---- epilogue: reduce partial l across lanes, then 3-way flash combine ----
    lrow += __shfl_xor(lrow, 16);
    lrow += __shfl_xor(lrow, 32);
    if (g4 == 0) { mfin[g * 64 + irow] = mrow; lfin[g * 64 + irow] = lrow; }
    __syncthreads();

    if (tid < 192) {
        const int gg = tid >> 6, i = tid & 63;
        const float m0 = mfin[i], m1 = mfin[64 + i], m2 = mfin[128 + i];
        const float M  = fmaxf(fmaxf(m0, m1), m2);
        const float e0 = fexp2(m0 - M), e1 = fexp2(m1 - M), e2 = fexp2(m2 - M);
        const float den = lfin[i] * e0 + lfin[64 + i] * e1 + lfin[128 + i] * e2;
        wfac[gg * 64 + i] = ((gg == 0) ? e0 : (gg == 1) ? e1 : e2) / den;
    }
    __syncthreads();   // loop LDS dead; Ocomb aliases it from here

#pragma unroll
    for (int gg = 0; gg < 3; ++gg) {
        if (g == gg) {
#pragma unroll
            for (int is = 0; is < 4; ++is) {
                const f32x4 f = *reinterpret_cast<const f32x4*>(
                    wfac + g * 64 + is * 16 + g4 * 4);
#pragma unroll
                for (int cs = 0; cs < 4; ++cs)
#pragma unroll
                    for (int r = 0; r < 4; ++r) {
                        const int i = is * 16 + g4 * 4 + r;
                        const int c = ws * 64 + cs * 16 + m16;
                        if (gg == 0) Ocomb[i * 260 + c]  = oacc[is][cs][r] * f[r];
                        else         Ocomb[i * 260 + c] += oacc[is][cs][r] * f[r];
                    }
            }
        }
        __syncthreads();
    }

    const float gm = gamma[0];
#pragma unroll 1
    for (int q = tid; q < 4096; q += 768) {
        const int c  = q >> 4;
        const int ib = (q & 15) * 4;
        f32x4 o;
#pragma unroll
        for (int u = 0; u < 4; ++u) o[u] = Ocomb[(ib + u) * 260 + c];
        const size_t idx = ((size_t)(b * CD + c)) * ND + i0 + ib;
        const f32x4 xv = *reinterpret_cast<const f32x4*>(x + idx);
        f32x4 res;
#pragma unroll
        for (int u = 0; u < 4; ++u) res[u] = gm * o[u] + xv[u];
        *reinterpret_cast<f32x4*>(out + idx) = res;
    }
}

extern "C" void kernel_launch(void* const* d_in, const int* in_sizes, int n_in,
                              void* d_out, int out_size, void* d_ws, size_t ws_size,
                              hipStream_t stream) {
    const float* x     = (const float*)d_in[0];
    const float* wq    = (const float*)d_in[1];
    const float* bq    = (const float*)d_in[2];
    const float* wk    = (const float*)d_in[3];
    const float* bk    = (const float*)d_in[4];
    const float* wv    = (const float*)d_in[5];
    const float* bv    = (const float*)d_in[6];
    const float* gamma = (const float*)d_in[7];

    unsigned short* Qt = (unsigned short*)d_ws;               // 1MB (scaled by log2e)
    unsigned short* Kt = Qt + (size_t)NB * ND * CQ;           // 1MB
    unsigned short* Vp = Kt + (size_t)NB * ND * CQ;           // 8MB packed frags
    unsigned short* Wh = Vp + (size_t)NB * CD * ND;           // 160KB
    float* out = (float*)d_out;

    wcvt_kernel<<<dim3(80),      dim3(256), 0, stream>>>(wq, wk, wv, Wh);
    proj_kernel<<<dim3(NB * 64), dim3(320), 0, stream>>>(x, Wh, bq, bk, bv, Qt, Kt, Vp);
    attn_kernel<<<dim3(NB * 64), dim3(768), 0, stream>>>(Qt, Kt, Vp, x, gamma, out);
}

// Round 15
// 74.819 us; speedup vs baseline: 3.3332x; 1.9246x over previous
//
#include <hip/hip_runtime.h>
#include <stdint.h>

// SelfAttentionBlock: B=4, C=256, H=W=64 (N=4096), CQK=32.
//   proj: grid 512 (b, 32-n tile) = 2 blocks/CU. W loaded f32->f16 in-register
//         (wcvt kernel deleted). x-transpose via 16KB swizzled LDS. Register
//         MFMA GEMM -> Qt[n][32]*log2e, Kt[n][32], Vp packed PV-B-frag order.
//   attn: r12 EXACTLY (768 thr = 3 j-groups x 4 waves, V direct from L2 via
//         Vp frags, K reg prefetch, swapped QK^T, shuffle-free defer-max
//         softmax, P dbuf LDS, group-local counter sync) + GSYNC fast path.

#define NB 4
#define CD 256
#define ND 4096
#define CQ 32
#define LOG2E 1.4426950408889634f

typedef __attribute__((ext_vector_type(4))) float f32x4;
typedef __attribute__((ext_vector_type(8))) _Float16 f16x8;
typedef __attribute__((ext_vector_type(4))) unsigned short u16x4;
typedef __attribute__((ext_vector_type(2))) unsigned int u32x2;
typedef __attribute__((ext_vector_type(4))) unsigned int u32x4;
typedef __attribute__((ext_vector_type(4))) int i32x4;

static __device__ __forceinline__ unsigned short f2h(float f) {
    union { _Float16 h; unsigned short u; } cv; cv.h = (_Float16)f; return cv.u;
}
static __device__ __forceinline__ float fexp2(float xv) {
    float r; asm("v_exp_f32 %0, %1" : "=v"(r) : "v"(xv)); return r;
}

// ---------------- projection: f32 W + fused x-transpose + register MFMA GEMM ----------------
// grid 512 = (b, 32-n tile), 320 threads = 5 waves, 2 blocks/CU.
// wave 0: Q,K rows (D[c][n]); waves 1-4: V rows swapped (D[n][c]) -> packed Vp.
__global__ __launch_bounds__(320) void proj_kernel(
    const float* __restrict__ x,
    const float* __restrict__ wq, const float* __restrict__ wk,
    const float* __restrict__ wv,
    const float* __restrict__ bq, const float* __restrict__ bk,
    const float* __restrict__ bv,
    unsigned short* __restrict__ Qt, unsigned short* __restrict__ Kt,
    unsigned short* __restrict__ Vp)
{
    __shared__ __align__(16) unsigned char xls[32 * 512];   // 16KB: [n][c] f16 swizzled

    const int tid = threadIdx.x;
    const int lane = tid & 63;
    const int w = __builtin_amdgcn_readfirstlane(tid >> 6);
    const int m16 = lane & 15, g4 = lane >> 4;
    // XCD swizzle over 512 blocks
    const int wgp = (blockIdx.x & 7) * 64 + (blockIdx.x >> 3);
    const int b = wgp >> 7, n0 = (wgp & 127) << 5;

    {   // phase 1: load x[b][0:256][n0:n0+32] f32 -> LDS transpose f16
        const float* xb = x + (size_t)b * CD * ND + n0;
#pragma unroll 1
        for (int idx = tid; idx < 2048; idx += 320) {
            const int c = idx >> 3, nq = (idx & 7) << 2;
            const f32x4 v = *reinterpret_cast<const f32x4*>(xb + (size_t)c * ND + nq);
#pragma unroll
            for (int r = 0; r < 4; ++r) {
                const int row = nq + r;
                const int ad = (row * 512 + c * 2) ^ ((row & 7) << 4);
                *reinterpret_cast<unsigned short*>(&xls[ad]) = f2h(v[r]);
            }
        }
    }
    __syncthreads();

    // W row pointers (f32) for this wave's 4 m-subtiles
    const float* wr[4];
#pragma unroll
    for (int ms = 0; ms < 4; ++ms) {
        if (w == 0) wr[ms] = (ms < 2) ? (wq + (size_t)(ms * 16 + m16) * CD)
                                      : (wk + (size_t)((ms - 2) * 16 + m16) * CD);
        else        wr[ms] = wv + (size_t)((w - 1) * 64 + ms * 16 + m16) * CD;
    }

    auto ldw = [&](const float* p) -> f16x8 {   // f32x8 -> f16x8 (rtz pack)
        const f32x4 a = *reinterpret_cast<const f32x4*>(p);
        const f32x4 c = *reinterpret_cast<const f32x4*>(p + 4);
        u32x4 u;
        u[0] = __builtin_bit_cast(unsigned int, __builtin_amdgcn_cvt_pkrtz(a[0], a[1]));
        u[1] = __builtin_bit_cast(unsigned int, __builtin_amdgcn_cvt_pkrtz(a[2], a[3]));
        u[2] = __builtin_bit_cast(unsigned int, __builtin_amdgcn_cvt_pkrtz(c[0], c[1]));
        u[3] = __builtin_bit_cast(unsigned int, __builtin_amdgcn_cvt_pkrtz(c[2], c[3]));
        return __builtin_bit_cast(f16x8, u);
    };

    f32x4 acc[4][2];
#pragma unroll
    for (int a = 0; a < 4; ++a)
#pragma unroll
        for (int c = 0; c < 2; ++c) acc[a][c] = (f32x4){0.f, 0.f, 0.f, 0.f};

    const int bswz = (m16 & 7) << 4;

#pragma unroll
    for (int ks = 0; ks < 8; ++ks) {
        const int ko = ks * 32 + g4 * 8;
        f16x8 af[4], bf[2];
#pragma unroll
        for (int ms = 0; ms < 4; ++ms) af[ms] = ldw(wr[ms] + ko);
#pragma unroll
        for (int ns = 0; ns < 2; ++ns) {
            const int ad = ((ns * 16 + m16) * 512 + ko * 2) ^ bswz;
            bf[ns] = *reinterpret_cast<const f16x8*>(&xls[ad]);
        }
        if (w == 0) {
#pragma unroll
            for (int ms = 0; ms < 4; ++ms)
#pragma unroll
                for (int ns = 0; ns < 2; ++ns)
                    acc[ms][ns] = __builtin_amdgcn_mfma_f32_16x16x32_f16(
                        af[ms], bf[ns], acc[ms][ns], 0, 0, 0);
        } else {
#pragma unroll
            for (int ms = 0; ms < 4; ++ms)
#pragma unroll
                for (int ns = 0; ns < 2; ++ns)
                    acc[ms][ns] = __builtin_amdgcn_mfma_f32_16x16x32_f16(
                        bf[ns], af[ms], acc[ms][ns], 0, 0, 0);
        }
    }

    if (w == 0) {   // Q (ms 0,1) + K (ms 2,3): D[c][n], col = m16 = n
#pragma unroll
        for (int ms = 0; ms < 4; ++ms) {
            const int seg = ms * 16;
            const int mb  = seg + g4 * 4;
            const f32x4 bias = (seg < 32) ? *reinterpret_cast<const f32x4*>(bq + mb)
                                          : *reinterpret_cast<const f32x4*>(bk + (mb - 32));
#pragma unroll
            for (int ns = 0; ns < 2; ++ns) {
                const int n = n0 + ns * 16 + m16;
                u16x4 h;
                if (seg < 32) {
#pragma unroll
                    for (int r = 0; r < 4; ++r)
                        h[r] = f2h(fmaxf(acc[ms][ns][r] + bias[r], 0.f) * LOG2E);
                    *reinterpret_cast<u16x4*>(Qt + ((size_t)(b * ND + n)) * CQ + mb) = h;
                } else {
#pragma unroll
                    for (int r = 0; r < 4; ++r)
                        h[r] = f2h(fmaxf(acc[ms][ns][r] + bias[r], 0.f));
                    *reinterpret_cast<u16x4*>(Kt + ((size_t)(b * ND + n)) * CQ + (mb - 32)) = h;
                }
            }
        }
    } else {        // V: D[n][c], rows n = g4*4+r, cols c = m16
        const int cbase = (w - 1) * 64;
#pragma unroll
        for (int ms = 0; ms < 4; ++ms) {
            const int c = cbase + ms * 16 + m16;
            const float bval = bv[c];
#pragma unroll
            for (int ns = 0; ns < 2; ++ns) {
                const int n = n0 + ns * 16 + g4 * 4;
                u16x4 h;
#pragma unroll
                for (int r = 0; r < 4; ++r)
                    h[r] = f2h(fmaxf(acc[ms][ns][r] + bval, 0.f));
                unsigned short* dst = Vp
                    + ((size_t)((b * 128 + (n >> 5)) * 16 + (c >> 4))) * 512
                    + ((((n >> 3) & 3) * 16 + (c & 15)) * 8) + (n & 7);
                *reinterpret_cast<u16x4*>(dst) = h;
            }
        }
    }
}

// ---------------- flash attention: r12 structure + GSYNC fast path ----------------
// grid: NB*64 blocks (b, 64-row i-strip), 768 threads (12 waves, 3 waves/SIMD).
// Group g owns 64-j chunks [cbase[g], cbase[g+1]) of 64 chunks total (22/21/21).
__global__ __launch_bounds__(768) void attn_kernel(
    const unsigned short* __restrict__ Qt, const unsigned short* __restrict__ Kt,
    const unsigned short* __restrict__ Vp, const float* __restrict__ x,
    const float* __restrict__ gamma, float* __restrict__ out)
{
    // 0..49151      p_lds   [3 groups][2 buf][64 i][128 B]  (f16, XOR-swizzled)
    // 49152..50687  scales  [3][2][64] f32
    // 50688..50783  flags   [3][2][4]  i32
    // epilogue: Ocomb [64][260] f32 @0 (aliases); mfin@66560 lfin@67328 wfac@68096
    __shared__ __align__(16) unsigned char smem[68864];
    __shared__ int gctr[3];
    float* scales = reinterpret_cast<float*>(smem + 49152);
    int*   flags  = reinterpret_cast<int*>(smem + 50688);
    float* Ocomb  = reinterpret_cast<float*>(smem);
    float* mfin   = reinterpret_cast<float*>(smem + 66560);  // [3][64]
    float* lfin   = reinterpret_cast<float*>(smem + 67328);  // [3][64]
    float* wfac   = reinterpret_cast<float*>(smem + 68096);  // [3][64]

    const int tid  = threadIdx.x;
    const int lane = tid & 63;
    const int w12  = __builtin_amdgcn_readfirstlane(tid >> 6);
    const int g    = (w12 >= 8) ? 2 : (w12 >> 2);   // groups: waves 0-3,4-7,8-11
    const int ws   = (w12 >= 8) ? (w12 - 8) : (w12 & 3);
    const int m16  = lane & 15;
    const int g4   = lane >> 4;
    const int wg   = (blockIdx.x & 7) * 32 + (blockIdx.x >> 3);  // XCD swizzle
    const int b    = wg >> 6;
    const int i0   = (wg & 63) << 6;

    if (tid < 3) gctr[tid] = 0;
    __syncthreads();   // counter init visible before any bump

    // Q as B-operand: col=i=ws*16+m16, k=g4*8+u
    const f16x8 qfrag = *reinterpret_cast<const f16x8*>(
        Qt + ((size_t)(b * ND + i0 + ws * 16 + m16)) * CQ + g4 * 8);
    // K as A-operand from global: row j=m16 (+16*jt), k=g4*8+u
    const unsigned short* kb = Kt + ((size_t)(b * ND + m16)) * CQ + g4 * 8;
    // V B-frags, packed layout: 16B/lane, 1KB/wave contiguous per frag
    const unsigned short* vpc =
        Vp + ((size_t)(b * 128 * 16 + ws * 4)) * 512 + lane * 8;

    f32x4 oacc[4][4];
#pragma unroll
    for (int a = 0; a < 4; ++a)
#pragma unroll
        for (int c = 0; c < 4; ++c) oacc[a][c] = (f32x4){0.f, 0.f, 0.f, 0.f};
    float mrow = -1e30f;
    float lrow = 0.f;    // per-lane PARTIAL row sum; reduced in epilogue
    const f32x4 zero4 = {0.f, 0.f, 0.f, 0.f};

    const int cbase  = (g == 0) ? 0 : (g == 1) ? 22 : 43;
    const int nsteps = (g == 0) ? 22 : 21;
    const int irow   = ws * 16 + m16;
    const int iswz   = (m16 & 7) << 4;

    auto LOADK = [&](f16x8 (&kr)[4], int j) {
#pragma unroll
        for (int t = 0; t < 4; ++t)
            kr[t] = *reinterpret_cast<const f16x8*>(kb + (size_t)(j + t * 16) * CQ);
    };

    // group-local sync with fast path: check once before sleeping.
    auto GSYNC = [&](int s) {
        asm volatile("s_waitcnt lgkmcnt(0)" ::: "memory");
        if (lane == 0) atomicAdd(&gctr[g], 1);
        const int tgt = (s + 1) * 4;
        int cv = __builtin_amdgcn_readfirstlane(*(volatile int*)&gctr[g]);
        while (cv < tgt) {
            __builtin_amdgcn_s_sleep(1);
            cv = __builtin_amdgcn_readfirstlane(*(volatile int*)&gctr[g]);
        }
    };

    auto STEP = [&](int s, f16x8 (&kc)[4], f16x8 (&kn)[4]) {
        const int j0  = (cbase + s) * 64;
        const int par = s & 1;
        unsigned char* pb = smem + g * 16384 + par * 8192;

        // issue V frag loads now; consumed after the sync (latency hidden)
        const int jblk0 = j0 >> 5;
        f16x8 vf[2][4];
#pragma unroll
        for (int jhh = 0; jhh < 2; ++jhh)
#pragma unroll
            for (int cs = 0; cs < 4; ++cs)
                vf[jhh][cs] = *reinterpret_cast<const f16x8*>(
                    vpc + (size_t)((jblk0 + jhh) * 16 + cs) * 512);
        // prefetch next step's K
        const int jn = (s + 1 < nsteps) ? (j0 + 64) : cbase * 64;
        LOADK(kn, jn);

        // ---- QK^T swapped: D[j][i], col=i=irow, lane holds 16 j values ----
        f32x4 sv[4];
#pragma unroll
        for (int t = 0; t < 4; ++t)
            sv[t] = __builtin_amdgcn_mfma_f32_16x16x32_f16(kc[t], qfrag, zero4, 0, 0, 0);

        // ---- softmax (log2 domain): shuffle-free common path ----
        float pm = sv[0][0];
#pragma unroll
        for (int t = 0; t < 4; ++t)
#pragma unroll
            for (int r = 0; r < 4; ++r) pm = fmaxf(pm, sv[t][r]);
        float sc = 1.0f;
        int myresc = 0;
        if (__ballot(pm <= mrow + 8.0f) != ~0ull) {
            float pr = fmaxf(pm, __shfl_xor(pm, 16));
            pr = fmaxf(pr, __shfl_xor(pr, 32));
            const float mnew = fmaxf(mrow, pr);
            sc = fexp2(mrow - mnew);
            mrow = mnew;
            myresc = 1;
        }
        float rs = 0.f;
#pragma unroll
        for (int t = 0; t < 4; ++t)
#pragma unroll
            for (int r = 0; r < 4; ++r) { sv[t][r] = fexp2(sv[t][r] - mrow); rs += sv[t][r]; }
        lrow = lrow * sc + rs;

        // ---- P -> LDS (4x ds_write_b64, swizzled) + scale + flag ----
#pragma unroll
        for (int t = 0; t < 4; ++t) {
            u32x2 pw;
            pw[0] = __builtin_bit_cast(unsigned int,
                        __builtin_amdgcn_cvt_pkrtz(sv[t][0], sv[t][1]));
            pw[1] = __builtin_bit_cast(unsigned int,
                        __builtin_amdgcn_cvt_pkrtz(sv[t][2], sv[t][3]));
            const int lo = (irow * 128 + t * 32 + g4 * 8) ^ iswz;
            *reinterpret_cast<u32x2*>(pb + lo) = pw;
        }
        if (g4 == 0)   scales[(g * 2 + par) * 64 + irow] = sc;
        if (lane == 0) flags[(g * 2 + par) * 4 + ws] = myresc;

        GSYNC(s);   // group-local; other groups unconstrained

        // ---- rescale oacc if any row of the group rescaled ----
        const i32x4 fl = *reinterpret_cast<const i32x4*>(flags + (g * 2 + par) * 4);
        const int anyresc = __builtin_amdgcn_readfirstlane(fl[0] | fl[1] | fl[2] | fl[3]);
        if (anyresc) {
#pragma unroll
            for (int is = 0; is < 4; ++is) {
                const f32x4 sr = *reinterpret_cast<const f32x4*>(
                    scales + (g * 2 + par) * 64 + is * 16 + g4 * 4);
#pragma unroll
                for (int r = 0; r < 4; ++r)
#pragma unroll
                    for (int cs = 0; cs < 4; ++cs) oacc[is][cs][r] *= sr[r];
            }
        }

        // ---- PV: P A-frags from LDS, V B-frags in registers ----
        __builtin_amdgcn_s_setprio(1);
#pragma unroll
        for (int jhh = 0; jhh < 2; ++jhh) {
#pragma unroll
            for (int is = 0; is < 4; ++is) {
                const int lo = ((is * 16 + m16) * 128 + jhh * 64 + g4 * 16) ^ iswz;
                const f16x8 pf = *reinterpret_cast<const f16x8*>(pb + lo);
#pragma unroll
                for (int cs = 0; cs < 4; ++cs)
                    oacc[is][cs] = __builtin_amdgcn_mfma_f32_16x16x32_f16(
                        pf, vf[jhh][cs], oacc[is][cs], 0, 0, 0);
            }
        }
        __builtin_amdgcn_s_setprio(0);
    };

    f16x8 kA[4], kB[4];
    LOADK(kA, cbase * 64);

#pragma unroll 1
    for (int s2 = 0; s2 < 11; ++s2) {
        const int s0 = 2 * s2, s1 = s0 + 1;
        if (s0 >= nsteps) break;
        STEP(s0, kA, kB);
        if (s1 >= nsteps) break;
        STEP(s1, kB, kA);
    }

    // ---- epilogue: reduce partial l across lanes, then 3-way flash combine ----
    lrow += __shfl_xor(lrow, 16);
    lrow += __shfl_xor(lrow, 32);
    if (g4 == 0) { mfin[g * 64 + irow] = mrow; lfin[g * 64 + irow] = lrow; }
    __syncthreads();

    if (tid < 192) {
        const int gg = tid >> 6, i = tid & 63;
        const float m0 = mfin[i], m1 = mfin[64 + i], m2 = mfin[128 + i];
        const float M  = fmaxf(fmaxf(m0, m1), m2);
        const float e0 = fexp2(m0 - M), e1 = fexp2(m1 - M), e2 = fexp2(m2 - M);
        const float den = lfin[i] * e0 + lfin[64 + i] * e1 + lfin[128 + i] * e2;
        wfac[gg * 64 + i] = ((gg == 0) ? e0 : (gg == 1) ? e1 : e2) / den;
    }
    __syncthreads();   // loop LDS dead; Ocomb aliases it from here

#pragma unroll
    for (int gg = 0; gg < 3; ++gg) {
        if (g == gg) {
#pragma unroll
            for (int is = 0; is < 4; ++is) {
                const f32x4 f = *reinterpret_cast<const f32x4*>(
                    wfac + g * 64 + is * 16 + g4 * 4);
#pragma unroll
                for (int cs = 0; cs < 4; ++cs)
#pragma unroll
                    for (int r = 0; r < 4; ++r) {
                        const int i = is * 16 + g4 * 4 + r;
                        const int c = ws * 64 + cs * 16 + m16;
                        if (gg == 0) Ocomb[i * 260 + c]  = oacc[is][cs][r] * f[r];
                        else         Ocomb[i * 260 + c] += oacc[is][cs][r] * f[r];
                    }
            }
        }
        __syncthreads();
    }

    const float gm = gamma[0];
#pragma unroll 1
    for (int q = tid; q < 4096; q += 768) {
        const int c  = q >> 4;
        const int ib = (q & 15) * 4;
        f32x4 o;
#pragma unroll
        for (int u = 0; u < 4; ++u) o[u] = Ocomb[(ib + u) * 260 + c];
        const size_t idx = ((size_t)(b * CD + c)) * ND + i0 + ib;
        const f32x4 xv = *reinterpret_cast<const f32x4*>(x + idx);
        f32x4 res;
#pragma unroll
        for (int u = 0; u < 4; ++u) res[u] = gm * o[u] + xv[u];
        *reinterpret_cast<f32x4*>(out + idx) = res;
    }
}

extern "C" void kernel_launch(void* const* d_in, const int* in_sizes, int n_in,
                              void* d_out, int out_size, void* d_ws, size_t ws_size,
                              hipStream_t stream) {
    const float* x     = (const float*)d_in[0];
    const float* wq    = (const float*)d_in[1];
    const float* bq    = (const float*)d_in[2];
    const float* wk    = (const float*)d_in[3];
    const float* bk    = (const float*)d_in[4];
    const float* wv    = (const float*)d_in[5];
    const float* bv    = (const float*)d_in[6];
    const float* gamma = (const float*)d_in[7];

    unsigned short* Qt = (unsigned short*)d_ws;               // 1MB (scaled by log2e)
    unsigned short* Kt = Qt + (size_t)NB * ND * CQ;           // 1MB
    unsigned short* Vp = Kt + (size_t)NB * ND * CQ;           // 8MB packed frags
    float* out = (float*)d_out;

    proj_kernel<<<dim3(512),     dim3(320), 0, stream>>>(x, wq, wk, wv, bq, bk, bv,
                                                         Qt, Kt, Vp);
    attn_kernel<<<dim3(NB * 64), dim3(768), 0, stream>>>(Qt, Kt, Vp, x, gamma, out);
}

// Round 16
// 67.062 us; speedup vs baseline: 3.7187x; 1.1157x over previous
//
#include <hip/hip_runtime.h>
#include <stdint.h>

// SelfAttentionBlock: B=4, C=256, H=W=64 (N=4096), CQK=32.
//   wcvt: W fp32->f16 (Wh), 80 blocks.
//   proj: grid 256 (b, 64-n tile), 640 thr = 10 waves (2.5 waves/SIMD; r12 had
//         1.25). Each wave owns 32 output rows (w0=Q, w1=K, w2-9=V). Fused
//         x-transpose via 32KB swizzled LDS -> register MFMA GEMM ->
//         Qt[n][32]*log2e, Kt[n][32], Vp packed PV-B-fragment order.
//   attn: r12 structure (768 thr = 3 j-groups x 4 waves, V direct from L2 via
//         Vp frags, K reg prefetch, swapped QK^T, shuffle-free defer-max
//         softmax, P dbuf LDS, group-local counter sync) + GSYNC fast path.

#define NB 4
#define CD 256
#define ND 4096
#define CQ 32
#define LOG2E 1.4426950408889634f

typedef __attribute__((ext_vector_type(4))) float f32x4;
typedef __attribute__((ext_vector_type(8))) _Float16 f16x8;
typedef __attribute__((ext_vector_type(4))) unsigned short u16x4;
typedef __attribute__((ext_vector_type(2))) unsigned int u32x2;
typedef __attribute__((ext_vector_type(4))) int i32x4;

static __device__ __forceinline__ unsigned short f2h(float f) {
    union { _Float16 h; unsigned short u; } cv; cv.h = (_Float16)f; return cv.u;
}
static __device__ __forceinline__ float fexp2(float xv) {
    float r; asm("v_exp_f32 %0, %1" : "=v"(r) : "v"(xv)); return r;
}

// ---------------- wcvt: W fp32 -> f16 ----------------
__global__ __launch_bounds__(256) void wcvt_kernel(
    const float* __restrict__ wq, const float* __restrict__ wk,
    const float* __restrict__ wv, unsigned short* __restrict__ Wh)
{
    const int idx = blockIdx.x * 256 + threadIdx.x;   // 80 blocks
    const int m = idx >> 6, kq = (idx & 63) << 2;
    const float* src = (m < 32) ? (wq + (size_t)m * CD + kq)
                     : (m < 64) ? (wk + (size_t)(m - 32) * CD + kq)
                                : (wv + (size_t)(m - 64) * CD + kq);
    const f32x4 v = *reinterpret_cast<const f32x4*>(src);
    u16x4 h;
#pragma unroll
    for (int u = 0; u < 4; ++u) h[u] = f2h(v[u]);
    *reinterpret_cast<u16x4*>(Wh + (size_t)m * CD + kq) = h;
}

// ---------------- projection: fused x-transpose + register MFMA GEMM ----------------
// grid NB*64 (b, 64-n tile), 640 threads = 10 waves.
// wave 0: Q rows 0-31 (D[c][n]); wave 1: K rows 0-31 (D[c][n]);
// waves 2-9: V rows (w-2)*32.. (swapped, D[n][c]) -> packed Vp store.
__global__ __launch_bounds__(640) void proj_kernel(
    const float* __restrict__ x, const unsigned short* __restrict__ Wh,
    const float* __restrict__ bq, const float* __restrict__ bk,
    const float* __restrict__ bv,
    unsigned short* __restrict__ Qt, unsigned short* __restrict__ Kt,
    unsigned short* __restrict__ Vp)
{
    __shared__ __align__(16) unsigned char xls[64 * 512];   // 32KB: [n][c] f16 swizzled

    const int tid = threadIdx.x;
    const int lane = tid & 63;
    const int w = __builtin_amdgcn_readfirstlane(tid >> 6);  // 0..9
    const int m16 = lane & 15, g4 = lane >> 4;
    const int b = blockIdx.x >> 6, n0 = (blockIdx.x & 63) << 6;

    {   // phase 1: load x[b][0:256][n0:n0+64] f32 -> LDS transpose f16
        const float* xb = x + (size_t)b * CD * ND + n0;
#pragma unroll 1
        for (int idx = tid; idx < 4096; idx += 640) {
            const int c = idx >> 4, nq = (idx & 15) << 2;
            const f32x4 v = *reinterpret_cast<const f32x4*>(xb + (size_t)c * ND + nq);
#pragma unroll
            for (int r = 0; r < 4; ++r) {
                const int row = nq + r;
                const int ad = (row * 512 + c * 2) ^ ((row & 7) << 4);
                *reinterpret_cast<unsigned short*>(&xls[ad]) = f2h(v[r]);
            }
        }
    }
    __syncthreads();

    f32x4 acc[2][4];
#pragma unroll
    for (int a = 0; a < 2; ++a)
#pragma unroll
        for (int c = 0; c < 4; ++c) acc[a][c] = (f32x4){0.f, 0.f, 0.f, 0.f};

    // wave w owns global rows [w*32, w*32+32) of M=320 (= [wq;wk;wv])
    const unsigned short* Wrow = Wh + (size_t)(w * 32 + m16) * CD;
    const int bswz = (m16 & 7) << 4;
    const bool qk = (w < 2);

#pragma unroll
    for (int ks = 0; ks < 8; ++ks) {
        const int ko = ks * 32 + g4 * 8;
        f16x8 af[2], bf[4];
#pragma unroll
        for (int ms = 0; ms < 2; ++ms)
            af[ms] = *reinterpret_cast<const f16x8*>(Wrow + (size_t)ms * 16 * CD + ko);
#pragma unroll
        for (int ns = 0; ns < 4; ++ns) {
            const int ad = ((ns * 16 + m16) * 512 + ko * 2) ^ bswz;
            bf[ns] = *reinterpret_cast<const f16x8*>(&xls[ad]);
        }
        if (qk) {
#pragma unroll
            for (int ms = 0; ms < 2; ++ms)
#pragma unroll
                for (int ns = 0; ns < 4; ++ns)
                    acc[ms][ns] = __builtin_amdgcn_mfma_f32_16x16x32_f16(
                        af[ms], bf[ns], acc[ms][ns], 0, 0, 0);
        } else {
#pragma unroll
            for (int ms = 0; ms < 2; ++ms)
#pragma unroll
                for (int ns = 0; ns < 4; ++ns)
                    acc[ms][ns] = __builtin_amdgcn_mfma_f32_16x16x32_f16(
                        bf[ns], af[ms], acc[ms][ns], 0, 0, 0);
        }
    }

    if (w == 0) {        // Q: D[c][n], col = m16 = n, rows = q-channel
#pragma unroll
        for (int ms = 0; ms < 2; ++ms) {
            const int mb = ms * 16 + g4 * 4;
            const f32x4 bias = *reinterpret_cast<const f32x4*>(bq + mb);
#pragma unroll
            for (int ns = 0; ns < 4; ++ns) {
                const int n = n0 + ns * 16 + m16;
                u16x4 h;
#pragma unroll
                for (int r = 0; r < 4; ++r)
                    h[r] = f2h(fmaxf(acc[ms][ns][r] + bias[r], 0.f) * LOG2E);
                *reinterpret_cast<u16x4*>(Qt + ((size_t)(b * ND + n)) * CQ + mb) = h;
            }
        }
    } else if (w == 1) { // K: D[c][n]
#pragma unroll
        for (int ms = 0; ms < 2; ++ms) {
            const int mb = ms * 16 + g4 * 4;
            const f32x4 bias = *reinterpret_cast<const f32x4*>(bk + mb);
#pragma unroll
            for (int ns = 0; ns < 4; ++ns) {
                const int n = n0 + ns * 16 + m16;
                u16x4 h;
#pragma unroll
                for (int r = 0; r < 4; ++r)
                    h[r] = f2h(fmaxf(acc[ms][ns][r] + bias[r], 0.f));
                *reinterpret_cast<u16x4*>(Kt + ((size_t)(b * ND + n)) * CQ + mb) = h;
            }
        }
    } else {             // V: D[n][c], rows n = g4*4+r, cols c = m16
        const int cbase = (w - 2) * 32;
#pragma unroll
        for (int ms = 0; ms < 2; ++ms) {
            const int c = cbase + ms * 16 + m16;
            const float bval = bv[c];
#pragma unroll
            for (int ns = 0; ns < 4; ++ns) {
                const int n = n0 + ns * 16 + g4 * 4;
                u16x4 h;
#pragma unroll
                for (int r = 0; r < 4; ++r)
                    h[r] = f2h(fmaxf(acc[ms][ns][r] + bval, 0.f));
                unsigned short* dst = Vp
                    + ((size_t)((b * 128 + (n >> 5)) * 16 + (c >> 4))) * 512
                    + ((((n >> 3) & 3) * 16 + (c & 15)) * 8) + (n & 7);
                *reinterpret_cast<u16x4*>(dst) = h;
            }
        }
    }
}

// ---------------- flash attention: r12 structure + GSYNC fast path ----------------
// grid: NB*64 blocks (b, 64-row i-strip), 768 threads (12 waves, 3 waves/SIMD).
// Group g owns 64-j chunks [cbase[g], cbase[g+1]) of 64 chunks total (22/21/21).
__global__ __launch_bounds__(768) void attn_kernel(
    const unsigned short* __restrict__ Qt, const unsigned short* __restrict__ Kt,
    const unsigned short* __restrict__ Vp, const float* __restrict__ x,
    const float* __restrict__ gamma, float* __restrict__ out)
{
    // 0..49151      p_lds   [3 groups][2 buf][64 i][128 B]  (f16, XOR-swizzled)
    // 49152..50687  scales  [3][2][64] f32
    // 50688..50783  flags   [3][2][4]  i32
    // epilogue: Ocomb [64][260] f32 @0 (aliases); mfin@66560 lfin@67328 wfac@68096
    __shared__ __align__(16) unsigned char smem[68864];
    __shared__ int gctr[3];
    float* scales = reinterpret_cast<float*>(smem + 49152);
    int*   flags  = reinterpret_cast<int*>(smem + 50688);
    float* Ocomb  = reinterpret_cast<float*>(smem);
    float* mfin   = reinterpret_cast<float*>(smem + 66560);  // [3][64]
    float* lfin   = reinterpret_cast<float*>(smem + 67328);  // [3][64]
    float* wfac   = reinterpret_cast<float*>(smem + 68096);  // [3][64]

    const int tid  = threadIdx.x;
    const int lane = tid & 63;
    const int w12  = __builtin_amdgcn_readfirstlane(tid >> 6);
    const int g    = (w12 >= 8) ? 2 : (w12 >> 2);   // groups: waves 0-3,4-7,8-11
    const int ws   = (w12 >= 8) ? (w12 - 8) : (w12 & 3);
    const int m16  = lane & 15;
    const int g4   = lane >> 4;
    const int wg   = (blockIdx.x & 7) * 32 + (blockIdx.x >> 3);  // XCD swizzle
    const int b    = wg >> 6;
    const int i0   = (wg & 63) << 6;

    if (tid < 3) gctr[tid] = 0;
    __syncthreads();   // counter init visible before any bump

    // Q as B-operand: col=i=ws*16+m16, k=g4*8+u
    const f16x8 qfrag = *reinterpret_cast<const f16x8*>(
        Qt + ((size_t)(b * ND + i0 + ws * 16 + m16)) * CQ + g4 * 8);
    // K as A-operand from global: row j=m16 (+16*jt), k=g4*8+u
    const unsigned short* kb = Kt + ((size_t)(b * ND + m16)) * CQ + g4 * 8;
    // V B-frags, packed layout: 16B/lane, 1KB/wave contiguous per frag
    const unsigned short* vpc =
        Vp + ((size_t)(b * 128 * 16 + ws * 4)) * 512 + lane * 8;

    f32x4 oacc[4][4];
#pragma unroll
    for (int a = 0; a < 4; ++a)
#pragma unroll
        for (int c = 0; c < 4; ++c) oacc[a][c] = (f32x4){0.f, 0.f, 0.f, 0.f};
    float mrow = -1e30f;
    float lrow = 0.f;    // per-lane PARTIAL row sum; reduced in epilogue
    const f32x4 zero4 = {0.f, 0.f, 0.f, 0.f};

    const int cbase  = (g == 0) ? 0 : (g == 1) ? 22 : 43;
    const int nsteps = (g == 0) ? 22 : 21;
    const int irow   = ws * 16 + m16;
    const int iswz   = (m16 & 7) << 4;

    auto LOADK = [&](f16x8 (&kr)[4], int j) {
#pragma unroll
        for (int t = 0; t < 4; ++t)
            kr[t] = *reinterpret_cast<const f16x8*>(kb + (size_t)(j + t * 16) * CQ);
    };

    // group-local sync with fast path: check once before sleeping.
    auto GSYNC = [&](int s) {
        asm volatile("s_waitcnt lgkmcnt(0)" ::: "memory");
        if (lane == 0) atomicAdd(&gctr[g], 1);
        const int tgt = (s + 1) * 4;
        int cv = __builtin_amdgcn_readfirstlane(*(volatile int*)&gctr[g]);
        while (cv < tgt) {
            __builtin_amdgcn_s_sleep(1);
            cv = __builtin_amdgcn_readfirstlane(*(volatile int*)&gctr[g]);
        }
    };

    auto STEP = [&](int s, f16x8 (&kc)[4], f16x8 (&kn)[4]) {
        const int j0  = (cbase + s) * 64;
        const int par = s & 1;
        unsigned char* pb = smem + g * 16384 + par * 8192;

        // issue V frag loads now; consumed after the sync (latency hidden)
        const int jblk0 = j0 >> 5;
        f16x8 vf[2][4];
#pragma unroll
        for (int jhh = 0; jhh < 2; ++jhh)
#pragma unroll
            for (int cs = 0; cs < 4; ++cs)
                vf[jhh][cs] = *reinterpret_cast<const f16x8*>(
                    vpc + (size_t)((jblk0 + jhh) * 16 + cs) * 512);
        // prefetch next step's K
        const int jn = (s + 1 < nsteps) ? (j0 + 64) : cbase * 64;
        LOADK(kn, jn);

        // ---- QK^T swapped: D[j][i], col=i=irow, lane holds 16 j values ----
        f32x4 sv[4];
#pragma unroll
        for (int t = 0; t < 4; ++t)
            sv[t] = __builtin_amdgcn_mfma_f32_16x16x32_f16(kc[t], qfrag, zero4, 0, 0, 0);

        // ---- softmax (log2 domain): shuffle-free common path ----
        float pm = sv[0][0];
#pragma unroll
        for (int t = 0; t < 4; ++t)
#pragma unroll
            for (int r = 0; r < 4; ++r) pm = fmaxf(pm, sv[t][r]);
        float sc = 1.0f;
        int myresc = 0;
        if (__ballot(pm <= mrow + 8.0f) != ~0ull) {
            float pr = fmaxf(pm, __shfl_xor(pm, 16));
            pr = fmaxf(pr, __shfl_xor(pr, 32));
            const float mnew = fmaxf(mrow, pr);
            sc = fexp2(mrow - mnew);
            mrow = mnew;
            myresc = 1;
        }
        float rs = 0.f;
#pragma unroll
        for (int t = 0; t < 4; ++t)
#pragma unroll
            for (int r = 0; r < 4; ++r) { sv[t][r] = fexp2(sv[t][r] - mrow); rs += sv[t][r]; }
        lrow = lrow * sc + rs;

        // ---- P -> LDS (4x ds_write_b64, swizzled) + scale + flag ----
#pragma unroll
        for (int t = 0; t < 4; ++t) {
            u32x2 pw;
            pw[0] = __builtin_bit_cast(unsigned int,
                        __builtin_amdgcn_cvt_pkrtz(sv[t][0], sv[t][1]));
            pw[1] = __builtin_bit_cast(unsigned int,
                        __builtin_amdgcn_cvt_pkrtz(sv[t][2], sv[t][3]));
            const int lo = (irow * 128 + t * 32 + g4 * 8) ^ iswz;
            *reinterpret_cast<u32x2*>(pb + lo) = pw;
        }
        if (g4 == 0)   scales[(g * 2 + par) * 64 + irow] = sc;
        if (lane == 0) flags[(g * 2 + par) * 4 + ws] = myresc;

        GSYNC(s);   // group-local; other groups unconstrained

        // ---- rescale oacc if any row of the group rescaled ----
        const i32x4 fl = *reinterpret_cast<const i32x4*>(flags + (g * 2 + par) * 4);
        const int anyresc = __builtin_amdgcn_readfirstlane(fl[0] | fl[1] | fl[2] | fl[3]);
        if (anyresc) {
#pragma unroll
            for (int is = 0; is < 4; ++is) {
                const f32x4 sr = *reinterpret_cast<const f32x4*>(
                    scales + (g * 2 + par) * 64 + is * 16 + g4 * 4);
#pragma unroll
                for (int r = 0; r < 4; ++r)
#pragma unroll
                    for (int cs = 0; cs < 4; ++cs) oacc[is][cs][r] *= sr[r];
            }
        }

        // ---- PV: P A-frags from LDS, V B-frags in registers ----
        __builtin_amdgcn_s_setprio(1);
#pragma unroll
        for (int jhh = 0; jhh < 2; ++jhh) {
#pragma unroll
            for (int is = 0; is < 4; ++is) {
                const int lo = ((is * 16 + m16) * 128 + jhh * 64 + g4 * 16) ^ iswz;
                const f16x8 pf = *reinterpret_cast<const f16x8*>(pb + lo);
#pragma unroll
                for (int cs = 0; cs < 4; ++cs)
                    oacc[is][cs] = __builtin_amdgcn_mfma_f32_16x16x32_f16(
                        pf, vf[jhh][cs], oacc[is][cs], 0, 0, 0);
            }
        }
        __builtin_amdgcn_s_setprio(0);
    };

    f16x8 kA[4], kB[4];
    LOADK(kA, cbase * 64);

#pragma unroll 1
    for (int s2 = 0; s2 < 11; ++s2) {
        const int s0 = 2 * s2, s1 = s0 + 1;
        if (s0 >= nsteps) break;
        STEP(s0, kA, kB);
        if (s1 >= nsteps) break;
        STEP(s1, kB, kA);
    }

    // ---- epilogue: reduce partial l across lanes, then 3-way flash combine ----
    lrow += __shfl_xor(lrow, 16);
    lrow += __shfl_xor(lrow, 32);
    if (g4 == 0) { mfin[g * 64 + irow] = mrow; lfin[g * 64 + irow] = lrow; }
    __syncthreads();

    if (tid < 192) {
        const int gg = tid >> 6, i = tid & 63;
        const float m0 = mfin[i], m1 = mfin[64 + i], m2 = mfin[128 + i];
        const float M  = fmaxf(fmaxf(m0, m1), m2);
        const float e0 = fexp2(m0 - M), e1 = fexp2(m1 - M), e2 = fexp2(m2 - M);
        const float den = lfin[i] * e0 + lfin[64 + i] * e1 + lfin[128 + i] * e2;
        wfac[gg * 64 + i] = ((gg == 0) ? e0 : (gg == 1) ? e1 : e2) / den;
    }
    __syncthreads();   // loop LDS dead; Ocomb aliases it from here

#pragma unroll
    for (int gg = 0; gg < 3; ++gg) {
        if (g == gg) {
#pragma unroll
            for (int is = 0; is < 4; ++is) {
                const f32x4 f = *reinterpret_cast<const f32x4*>(
                    wfac + g * 64 + is * 16 + g4 * 4);
#pragma unroll
                for (int cs = 0; cs < 4; ++cs)
#pragma unroll
                    for (int r = 0; r < 4; ++r) {
                        const int i = is * 16 + g4 * 4 + r;
                        const int c = ws * 64 + cs * 16 + m16;
                        if (gg == 0) Ocomb[i * 260 + c]  = oacc[is][cs][r] * f[r];
                        else         Ocomb[i * 260 + c] += oacc[is][cs][r] * f[r];
                    }
            }
        }
        __syncthreads();
    }

    const float gm = gamma[0];
#pragma unroll 1
    for (int q = tid; q < 4096; q += 768) {
        const int c  = q >> 4;
        const int ib = (q & 15) * 4;
        f32x4 o;
#pragma unroll
        for (int u = 0; u < 4; ++u) o[u] = Ocomb[(ib + u) * 260 + c];
        const size_t idx = ((size_t)(b * CD + c)) * ND + i0 + ib;
        const f32x4 xv = *reinterpret_cast<const f32x4*>(x + idx);
        f32x4 res;
#pragma unroll
        for (int u = 0; u < 4; ++u) res[u] = gm * o[u] + xv[u];
        *reinterpret_cast<f32x4*>(out + idx) = res;
    }
}

extern "C" void kernel_launch(void* const* d_in, const int* in_sizes, int n_in,
                              void* d_out, int out_size, void* d_ws, size_t ws_size,
                              hipStream_t stream) {
    const float* x     = (const float*)d_in[0];
    const float* wq    = (const float*)d_in[1];
    const float* bq    = (const float*)d_in[2];
    const float* wk    = (const float*)d_in[3];
    const float* bk    = (const float*)d_in[4];
    const float* wv    = (const float*)d_in[5];
    const float* bv    = (const float*)d_in[6];
    const float* gamma = (const float*)d_in[7];

    unsigned short* Qt = (unsigned short*)d_ws;               // 1MB (scaled by log2e)
    unsigned short* Kt = Qt + (size_t)NB * ND * CQ;           // 1MB
    unsigned short* Vp = Kt + (size_t)NB * ND * CQ;           // 8MB packed frags
    unsigned short* Wh = Vp + (size_t)NB * CD * ND;           // 160KB
    float* out = (float*)d_out;

    wcvt_kernel<<<dim3(80),      dim3(256), 0, stream>>>(wq, wk, wv, Wh);
    proj_kernel<<<dim3(NB * 64), dim3(640), 0, stream>>>(x, Wh, bq, bk, bv, Qt, Kt, Vp);
    attn_kernel<<<dim3(NB * 64), dim3(768), 0, stream>>>(Qt, Kt, Vp, x, gamma, out);
}